// Round 10
// baseline (36.847 us; speedup 1.0000x reference)
//
#include <hip/hip_runtime.h>
#include <math.h>

#define NB 16
#define BQ 2048
#define NC 256
#define NL 255   // labels 0..254 (class 255 excluded)

typedef unsigned long long u64;
typedef unsigned int u32;
typedef unsigned short u16;
typedef unsigned char u8;

__device__ __forceinline__ u32 ord_f32(float f) {
  u32 b = __float_as_uint(f);
  return (b & 0x80000000u) ? ~b : (b | 0x80000000u);
}

// Kernel A: 16 lanes per query (4 queries per wave). PROVEN absmax=0 since r5 —
// arithmetic and reduction DAG must not change. Stages results to d_ws
// (immutable source for B; B writes only finals to d_out).
__global__ __launch_bounds__(256) void score_box_kernel(
    const float* __restrict__ logits,
    const float* __restrict__ pboxes,
    const int* __restrict__ tsz,
    float* __restrict__ ws)
{
#pragma clang fp contract(off)
  const int lane = threadIdx.x & 63;
  const int g = lane & 15;            // sub-lane within the 16-lane group
  const int wv = threadIdx.x >> 6;
  const int q = (blockIdx.x * 4 + wv) * 4 + (lane >> 4);  // 16 queries/block
  const float* row = logits + (size_t)q * NC + g * 16;
  const float4 la = *reinterpret_cast<const float4*>(row);
  const float4 lb4 = *reinterpret_cast<const float4*>(row + 4);
  const float4 lc = *reinterpret_cast<const float4*>(row + 8);
  const float4 ld = *reinterpret_cast<const float4*>(row + 12);

  float m = fmaxf(fmaxf(fmaxf(la.x, la.y), fmaxf(la.z, la.w)),
           fmaxf(fmaxf(fmaxf(lb4.x, lb4.y), fmaxf(lb4.z, lb4.w)),
           fmaxf(fmaxf(fmaxf(lc.x, lc.y), fmaxf(lc.z, lc.w)),
                 fmaxf(fmaxf(ld.x, ld.y), fmaxf(ld.z, ld.w)))));
  #pragma unroll
  for (int d = 1; d < 16; d <<= 1) m = fmaxf(m, __shfl_xor(m, d));

  float4 ea, eb, ec, ed;
  ea.x = expf(la.x - m);  ea.y = expf(la.y - m);  ea.z = expf(la.z - m);  ea.w = expf(la.w - m);
  eb.x = expf(lb4.x - m); eb.y = expf(lb4.y - m); eb.z = expf(lb4.z - m); eb.w = expf(lb4.w - m);
  ec.x = expf(lc.x - m);  ec.y = expf(lc.y - m);  ec.z = expf(lc.z - m);  ec.w = expf(lc.w - m);
  ed.x = expf(ld.x - m);  ed.y = expf(ld.y - m);  ed.z = expf(ld.z - m);  ed.w = expf(ld.w - m);

  float s = (((ea.x + ea.y) + (ea.z + ea.w)) + ((eb.x + eb.y) + (eb.z + eb.w)))
          + (((ec.x + ec.y) + (ec.z + ec.w)) + ((ed.x + ed.y) + (ed.z + ed.w)));
  #pragma unroll
  for (int d = 1; d < 16; d <<= 1) s += __shfl_xor(s, d);

  const int c0 = g * 16;
  float bp = ea.x / s; int bc = c0;
  float p;
  p = ea.y / s; if (p > bp) { bp = p; bc = c0 + 1; }
  p = ea.z / s; if (p > bp) { bp = p; bc = c0 + 2; }
  p = ea.w / s; if (p > bp) { bp = p; bc = c0 + 3; }
  p = eb.x / s; if (p > bp) { bp = p; bc = c0 + 4; }
  p = eb.y / s; if (p > bp) { bp = p; bc = c0 + 5; }
  p = eb.z / s; if (p > bp) { bp = p; bc = c0 + 6; }
  p = eb.w / s; if (p > bp) { bp = p; bc = c0 + 7; }
  p = ec.x / s; if (p > bp) { bp = p; bc = c0 + 8; }
  p = ec.y / s; if (p > bp) { bp = p; bc = c0 + 9; }
  p = ec.z / s; if (p > bp) { bp = p; bc = c0 + 10; }
  p = ec.w / s; if (p > bp) { bp = p; bc = c0 + 11; }
  p = ed.x / s; if (p > bp) { bp = p; bc = c0 + 12; }
  p = ed.y / s; if (p > bp) { bp = p; bc = c0 + 13; }
  p = ed.z / s; if (p > bp) { bp = p; bc = c0 + 14; }
  p = ed.w / s; if (g != 15 && p > bp) { bp = p; bc = c0 + 15; }  // skip class 255
  #pragma unroll
  for (int d = 1; d < 16; d <<= 1) {
    const float op = __shfl_xor(bp, d);
    const int   oc = __shfl_xor(bc, d);
    if (op > bp || (op == bp && oc < bc)) { bp = op; bc = oc; }
  }

  if (g == 0) {
    const int b = q >> 11;
    float hf = (float)tsz[b * 2 + 0];
    float wf = (float)tsz[b * 2 + 1];
    float4 pb = *reinterpret_cast<const float4*>(pboxes + (size_t)q * 4);
    float hw = 0.5f * pb.z, hh = 0.5f * pb.w;
    float4 ob;
    ob.x = (pb.x - hw) * wf;
    ob.y = (pb.y - hh) * hf;
    ob.z = (pb.x + hw) * wf;
    ob.w = (pb.y + hh) * hf;
    *reinterpret_cast<float4*>(ws + (size_t)q * 4) = ob;
    ws[NB * BQ * 4 + q] = bp;
    ws[NB * BQ * 5 + q] = (float)bc;
  }
}

// Kernel B: one 1024-thread block per batch. 6 segments / 5 barriers:
// load/compact (invalids exit to d_out directly) -> fused 3-counter rank pass
// (r7's item structure, u64 reads, u32 atomics -> no spill) -> sweep/place
// (+ fused valid writeback; boxes re-read from immutable d_ws) -> mask build
// -> per-label bitmask resolve writing keep_g. LDS ~80KB.
__global__ __launch_bounds__(1024) void sort_nms_kernel(
    const float* __restrict__ ws, float* __restrict__ out)
{
#pragma clang fp contract(off)
  __shared__ __align__(16) u64 cvk[BQ];  // compact valid keys; reused as masks
  __shared__ u32 rnk[BQ];                // rank (sorted position) accumulators
  __shared__ u32 lgl[BQ];                // packed (lgt<<16)|llt accumulators
  __shared__ float4 bxo[BQ];             // label-offset coords by sorted position
  __shared__ u32 stg_g[BQ];              // packed (st<<16)|g by sorted position
  __shared__ u16 gpos[BQ];               // sorted position by group slot
  __shared__ u8 grpk[BQ];                // fallback keep flags by group slot
  __shared__ u32 offl[256];              // group start by label (benign same-value race)
  __shared__ u32 kcnt[256];              // per-label member count
  __shared__ u32 wval[16], winv[16];     // per-wave valid/invalid counts

  const int b = blockIdx.x;
  const int tid = threadIdx.x;
  const int lane = tid & 63;
  const int wv = tid >> 6;
  const float* bws = ws + (size_t)b * BQ * 4;
  const float* sws = ws + NB * BQ * 4 + (size_t)b * BQ;
  const float* lws = ws + NB * BQ * 5 + (size_t)b * BQ;
  float* boxes_g  = out + (size_t)b * BQ * 4;
  float* scores_g = out + NB * BQ * 4 + (size_t)b * BQ;
  float* labels_g = out + NB * BQ * 5 + (size_t)b * BQ;
  float* keep_g   = out + NB * BQ * 6 + (size_t)b * BQ;

  // ---- segment 1: load, keys, per-wave counts, zero accumulators ----
  const int q0 = 2 * tid;
  float2 s2 = *reinterpret_cast<const float2*>(sws + q0);
  float2 lf = *reinterpret_cast<const float2*>(lws + q0);
  float4 bb0 = *reinterpret_cast<const float4*>(bws + (size_t)q0 * 4);
  float4 bb1 = *reinterpret_cast<const float4*>(bws + (size_t)q0 * 4 + 4);
  const u32 l0 = (u32)(int)lf.x, l1 = (u32)(int)lf.y;
  rnk[tid] = 0; rnk[tid + 1024] = 0;
  lgl[tid] = 0; lgl[tid + 1024] = 0;
  if (tid < 256) kcnt[tid] = 0;
  const bool v0 = (s2.x >= 0.05f), v1 = (s2.y >= 0.05f);
  // key: (ord<<32)|(idx<<8)|label — label bits below idx never decide order
  const u64 f0 = ((u64)ord_f32(s2.x) << 32) | ((u32)q0 << 8) | l0;
  const u64 f1 = ((u64)ord_f32(s2.y) << 32) | ((u32)(q0 + 1) << 8) | l1;
  const u64 b0 = __ballot(v0), b1 = __ballot(v1);
  if (lane == 0) {
    const u32 c = (u32)(__popcll(b0) + __popcll(b1));
    wval[wv] = c;
    winv[wv] = 128u - c;
  }
  __syncthreads();  // B0

  // ---- segment 2: compaction; invalids exit to d_out now ----
  int nv = 0, voff = 0, ioff = 0;
  #pragma unroll
  for (int w = 0; w < 16; ++w) {
    const int c = (int)wval[w];
    nv += c;
    if (w < wv) { voff += c; ioff += (int)winv[w]; }
  }
  const int tinv = BQ - nv;
  const u64 below = (1ull << lane) - 1ull;
  const int vr0 = voff + (int)__popcll(b0 & below) + (int)__popcll(b1 & below);
  const int ir0 = ioff + (int)__popcll(~b0 & below) + (int)__popcll(~b1 & below);
  const int vr1 = vr0 + (v0 ? 1 : 0);
  const int ir1 = ir0 + (v0 ? 0 : 1);
  // invalid tail position nv + (tinv-1-ir) = descending orig idx (exact
  // reversed-stable semantics for the -inf block; proven r3-r9)
  if (v0) cvk[vr0] = f0;
  else {
    const int ip = nv + (tinv - 1 - ir0);
    *reinterpret_cast<float4*>(boxes_g + (size_t)ip * 4) = bb0;
    scores_g[ip] = s2.x; labels_g[ip] = lf.x; keep_g[ip] = 0.0f;
  }
  if (v1) cvk[vr1] = f1;
  else {
    const int ip = nv + (tinv - 1 - ir1);
    *reinterpret_cast<float4*>(boxes_g + (size_t)ip * 4) = bb1;
    scores_g[ip] = s2.y; labels_g[ip] = lf.y; keep_g[ip] = 0.0f;
  }
  __syncthreads();  // B1

  // ---- segment 3: fused 3-counter rank pass (r7 item structure) ----
  // cgt = #greater (sorted position); lgt = #same-label greater (group rank);
  // llt = #smaller-label (group start). u64 reads unroll-8 (~30 live VGPRs).
  const int nvc = (nv + 63) >> 6;
  {
    const int nitems = nvc * nvc;
    for (int it = wv; it < nitems; it += 16) {
      const int sc_ = it / nvc;
      const int jc = it - sc_ * nvc;
      const int slot = (sc_ << 6) + lane;
      const u64 ki = cvk[slot];          // slot < 2048 always; junk harmless
      const u32 li = (u32)ki & 255u;
      const int j0 = jc << 6;
      int lim = nv - j0; if (lim > 64) lim = 64;
      const u64* jp = &cvk[j0];
      u32 cgt = 0, lgt = 0, llt = 0;
      #pragma unroll 8
      for (int l = 0; l < lim; ++l) {
        const u64 kj = jp[l];
        const u32 lj = (u32)kj & 255u;
        const u32 gx = (kj > ki) ? 1u : 0u;
        cgt += gx;
        lgt += gx & ((lj == li) ? 1u : 0u);
        llt += (lj < li) ? 1u : 0u;
      }
      if (slot < nv) {
        if (cgt) atomicAdd(&rnk[slot], cgt);
        if (lgt | llt) atomicAdd(&lgl[slot], (lgt << 16) | llt);
      }
    }
  }
  __syncthreads();  // B2

  // ---- segment 4: sweep — place by rank, fused valid writeback, grouping ----
  for (int slot = tid; slot < nv; slot += 1024) {
    const u64 ki = cvk[slot];
    const u32 p = rnk[slot];             // sorted position (descending key)
    const u32 ll = lgl[slot];
    const u32 lgt = ll >> 16, llt = ll & 0xFFFFu;
    const u32 oi = (u32)(ki >> 8) & (BQ - 1);
    const u32 li = (u32)ki & 255u;
    const float4 A = *reinterpret_cast<const float4*>(bws + (size_t)oi * 4);
    *reinterpret_cast<float4*>(boxes_g + (size_t)p * 4) = A;
    scores_g[p] = __uint_as_float((u32)(ki >> 32) & 0x7FFFFFFFu);  // exact bits
    labels_g[p] = (float)li;
    const float lc = (float)li * 100000.0f;
    float4 Ao;
    Ao.x = A.x + lc; Ao.y = A.y + lc; Ao.z = A.z + lc; Ao.w = A.w + lc;
    bxo[p] = Ao;
    gpos[llt + lgt] = (u16)p;
    stg_g[p] = (llt << 16) | lgt;
    offl[li] = llt;                      // same value for all of label li
    atomicAdd(&kcnt[li], 1u);
  }
  __syncthreads();  // B3

  // ---- segment 5: overlap bitmasks vs earlier same-label members ----
  // (cvk is dead as keys — reuse as the mask array)
  for (int p = tid; p < nv; p += 1024) {
    const u32 sg = stg_g[p];
    const u32 st = sg >> 16, g = sg & 0xFFFFu;
    if (g < 64) {
      const float4 Ao = bxo[p];
      const float areaA = fmaxf(Ao.z - Ao.x, 0.0f) * fmaxf(Ao.w - Ao.y, 0.0f);
      u64 m = 0;
      for (u32 r = 0; r < g; ++r) {
        const int p2 = gpos[st + r];
        const float4 Bo = bxo[p2];
        const float areaB = fmaxf(Bo.z - Bo.x, 0.0f) * fmaxf(Bo.w - Bo.y, 0.0f);
        const float ltx = fmaxf(Ao.x, Bo.x), lty = fmaxf(Ao.y, Bo.y);
        const float rbx = fminf(Ao.z, Bo.z), rby = fminf(Ao.w, Bo.w);
        const float iw = fmaxf(rbx - ltx, 0.0f), ih = fmaxf(rby - lty, 0.0f);
        const float inter = iw * ih;
        const float uni = (areaA + areaB) - inter;
        const float iou = inter / fmaxf(uni, 1e-6f);
        if (iou > 0.7f) m |= (1ull << r);
      }
      cvk[st + g] = m;
    }
  }
  __syncthreads();  // B4

  // ---- segment 6: per-label greedy resolution, writes keep_g directly ----
  if (tid < NL) {
    const int k = (int)kcnt[tid];
    if (k > 0) {
      const int st = (int)offl[tid];
      if (k <= 64) {
        u64 kept = 0;
        for (int r = 0; r < k; ++r) {
          const u64 m = cvk[st + r];
          const int keep = ((m & kept) == 0) ? 1 : 0;
          kept |= (u64)keep << r;
          keep_g[gpos[st + r]] = keep ? 1.0f : 0.0f;
        }
      } else {
        for (int a = 0; a < k; ++a) {
          const int p = gpos[st + a];
          const float4 Ao = bxo[p];
          const float areaA = fmaxf(Ao.z - Ao.x, 0.0f) * fmaxf(Ao.w - Ao.y, 0.0f);
          int keep = 1;
          for (int e = 0; e < a; ++e) {
            if (!grpk[st + e]) continue;
            const int p2 = gpos[st + e];
            const float4 Bo = bxo[p2];
            const float areaB = fmaxf(Bo.z - Bo.x, 0.0f) * fmaxf(Bo.w - Bo.y, 0.0f);
            const float ltx = fmaxf(Ao.x, Bo.x), lty = fmaxf(Ao.y, Bo.y);
            const float rbx = fminf(Ao.z, Bo.z), rby = fminf(Ao.w, Bo.w);
            const float iw = fmaxf(rbx - ltx, 0.0f), ih = fmaxf(rby - lty, 0.0f);
            const float inter = iw * ih;
            const float uni = (areaA + areaB) - inter;
            const float iou = inter / fmaxf(uni, 1e-6f);
            if (iou > 0.7f) { keep = 0; break; }
          }
          grpk[st + a] = (u8)keep;
          keep_g[p] = keep ? 1.0f : 0.0f;
        }
      }
    }
  }
}

extern "C" void kernel_launch(void* const* d_in, const int* in_sizes, int n_in,
                              void* d_out, int out_size, void* d_ws, size_t ws_size,
                              hipStream_t stream) {
  const float* logits = (const float*)d_in[0];
  const float* pboxes = (const float*)d_in[1];
  const int*   tsz    = (const int*)d_in[2];
  float* out = (float*)d_out;
  float* ws  = (float*)d_ws;
  score_box_kernel<<<NB * BQ / 16, 256, 0, stream>>>(logits, pboxes, tsz, ws);
  sort_nms_kernel<<<NB, 1024, 0, stream>>>(ws, out);
}

// Round 11
// 29.640 us; speedup vs baseline: 1.2432x; 1.2432x over previous
//
#include <hip/hip_runtime.h>
#include <math.h>

#define NB 16
#define BQ 2048
#define NC 256
#define NL 255   // labels 0..254 (class 255 excluded)

typedef unsigned long long u64;
typedef unsigned int u32;
typedef unsigned short u16;
typedef unsigned char u8;

__device__ __forceinline__ u32 ord_f32(float f) {
  u32 b = __float_as_uint(f);
  return (b & 0x80000000u) ? ~b : (b | 0x80000000u);
}

// Kernel A: 16 lanes per query (4 queries per wave). PROVEN absmax=0 since r5 —
// arithmetic and reduction DAG must not change.
__global__ __launch_bounds__(256) void score_box_kernel(
    const float* __restrict__ logits,
    const float* __restrict__ pboxes,
    const int* __restrict__ tsz,
    float* __restrict__ out)
{
#pragma clang fp contract(off)
  const int lane = threadIdx.x & 63;
  const int g = lane & 15;            // sub-lane within the 16-lane group
  const int wv = threadIdx.x >> 6;
  const int q = (blockIdx.x * 4 + wv) * 4 + (lane >> 4);  // 16 queries/block
  const float* row = logits + (size_t)q * NC + g * 16;
  const float4 la = *reinterpret_cast<const float4*>(row);
  const float4 lb4 = *reinterpret_cast<const float4*>(row + 4);
  const float4 lc = *reinterpret_cast<const float4*>(row + 8);
  const float4 ld = *reinterpret_cast<const float4*>(row + 12);

  float m = fmaxf(fmaxf(fmaxf(la.x, la.y), fmaxf(la.z, la.w)),
           fmaxf(fmaxf(fmaxf(lb4.x, lb4.y), fmaxf(lb4.z, lb4.w)),
           fmaxf(fmaxf(fmaxf(lc.x, lc.y), fmaxf(lc.z, lc.w)),
                 fmaxf(fmaxf(ld.x, ld.y), fmaxf(ld.z, ld.w)))));
  #pragma unroll
  for (int d = 1; d < 16; d <<= 1) m = fmaxf(m, __shfl_xor(m, d));

  float4 ea, eb, ec, ed;
  ea.x = expf(la.x - m);  ea.y = expf(la.y - m);  ea.z = expf(la.z - m);  ea.w = expf(la.w - m);
  eb.x = expf(lb4.x - m); eb.y = expf(lb4.y - m); eb.z = expf(lb4.z - m); eb.w = expf(lb4.w - m);
  ec.x = expf(lc.x - m);  ec.y = expf(lc.y - m);  ec.z = expf(lc.z - m);  ec.w = expf(lc.w - m);
  ed.x = expf(ld.x - m);  ed.y = expf(ld.y - m);  ed.z = expf(ld.z - m);  ed.w = expf(ld.w - m);

  float s = (((ea.x + ea.y) + (ea.z + ea.w)) + ((eb.x + eb.y) + (eb.z + eb.w)))
          + (((ec.x + ec.y) + (ec.z + ec.w)) + ((ed.x + ed.y) + (ed.z + ed.w)));
  #pragma unroll
  for (int d = 1; d < 16; d <<= 1) s += __shfl_xor(s, d);

  const int c0 = g * 16;
  float bp = ea.x / s; int bc = c0;
  float p;
  p = ea.y / s; if (p > bp) { bp = p; bc = c0 + 1; }
  p = ea.z / s; if (p > bp) { bp = p; bc = c0 + 2; }
  p = ea.w / s; if (p > bp) { bp = p; bc = c0 + 3; }
  p = eb.x / s; if (p > bp) { bp = p; bc = c0 + 4; }
  p = eb.y / s; if (p > bp) { bp = p; bc = c0 + 5; }
  p = eb.z / s; if (p > bp) { bp = p; bc = c0 + 6; }
  p = eb.w / s; if (p > bp) { bp = p; bc = c0 + 7; }
  p = ec.x / s; if (p > bp) { bp = p; bc = c0 + 8; }
  p = ec.y / s; if (p > bp) { bp = p; bc = c0 + 9; }
  p = ec.z / s; if (p > bp) { bp = p; bc = c0 + 10; }
  p = ec.w / s; if (p > bp) { bp = p; bc = c0 + 11; }
  p = ed.x / s; if (p > bp) { bp = p; bc = c0 + 12; }
  p = ed.y / s; if (p > bp) { bp = p; bc = c0 + 13; }
  p = ed.z / s; if (p > bp) { bp = p; bc = c0 + 14; }
  p = ed.w / s; if (g != 15 && p > bp) { bp = p; bc = c0 + 15; }  // skip class 255
  #pragma unroll
  for (int d = 1; d < 16; d <<= 1) {
    const float op = __shfl_xor(bp, d);
    const int   oc = __shfl_xor(bc, d);
    if (op > bp || (op == bp && oc < bc)) { bp = op; bc = oc; }
  }

  if (g == 0) {
    const int b = q >> 11;
    float hf = (float)tsz[b * 2 + 0];
    float wf = (float)tsz[b * 2 + 1];
    float4 pb = *reinterpret_cast<const float4*>(pboxes + (size_t)q * 4);
    float hw = 0.5f * pb.z, hh = 0.5f * pb.w;
    float4 ob;
    ob.x = (pb.x - hw) * wf;
    ob.y = (pb.y - hh) * hf;
    ob.z = (pb.x + hw) * wf;
    ob.w = (pb.y + hh) * hf;
    *reinterpret_cast<float4*>(out + (size_t)q * 4) = ob;
    out[NB * BQ * 4 + q] = bp;
    out[NB * BQ * 5 + q] = (float)bc;
  }
}

// Kernel B: one 1024-thread block per batch. r9 base (proven 30.16us) with ONE
// change: the rank pass is register-blocked (4 slot-keys/lane x b128 j-reads =
// 8 pairs per DS instruction), cutting LDS-pipe instructions 4096 -> ~550.
__global__ __launch_bounds__(1024) void sort_nms_kernel(float* __restrict__ out)
{
#pragma clang fp contract(off)
  __shared__ __align__(16) u64 cvk[BQ];  // compact valid keys (0-padded); reused as masks
  __shared__ u32 cgt_a[BQ];              // per-slot rank accumulators
  __shared__ float4 bx[BQ];              // boxes by orig idx
  __shared__ float4 bxo[BQ];             // label-offset coords by sorted position
  __shared__ u32 sco[BQ];                // score bits by sorted position
  __shared__ u8 lbp[BQ];                 // label by sorted position (255 = pad)
  __shared__ u16 sidx[BQ];               // orig idx by sorted position
  __shared__ u16 gpos[BQ];               // sorted position by group slot
  __shared__ u8 grpk[BQ];                // fallback keep flags by group slot
  __shared__ u16 hist[32 * 256];         // [chunk][label] counts -> excl prefix
  __shared__ u32 tot[256];               // per-label totals
  __shared__ u32 scn[256];               // inclusive label-count scan
  __shared__ u32 wval[16], winv[16];     // per-wave valid/invalid counts

  const int b = blockIdx.x;
  const int tid = threadIdx.x;
  const int lane = tid & 63;
  const int wv = tid >> 6;
  float* boxes_g  = out + (size_t)b * BQ * 4;
  float* scores_g = out + NB * BQ * 4 + (size_t)b * BQ;
  float* labels_g = out + NB * BQ * 5 + (size_t)b * BQ;
  float* keep_g   = out + NB * BQ * 6 + (size_t)b * BQ;

  // ---- phase 1: load, stage, zero accumulators ----
  const int q0 = 2 * tid;
  float2 s2 = *reinterpret_cast<const float2*>(scores_g + q0);
  float2 lf = *reinterpret_cast<const float2*>(labels_g + q0);
  float4 bb0 = *reinterpret_cast<const float4*>(boxes_g + (size_t)q0 * 4);
  float4 bb1 = *reinterpret_cast<const float4*>(boxes_g + (size_t)q0 * 4 + 4);
  const u32 l0 = (u32)(int)lf.x, l1 = (u32)(int)lf.y;
  bx[q0] = bb0; bx[q0 + 1] = bb1;
  cgt_a[tid] = 0; cgt_a[tid + 1024] = 0;
  reinterpret_cast<u32*>(hist)[tid]        = 0;
  reinterpret_cast<u32*>(hist)[tid + 1024] = 0;
  reinterpret_cast<u32*>(hist)[tid + 2048] = 0;
  reinterpret_cast<u32*>(hist)[tid + 3072] = 0;
  const bool v0 = (s2.x >= 0.05f), v1 = (s2.y >= 0.05f);
  // key: (ord<<32)|(idx<<8)|label — label bits below idx never decide order
  const u64 f0 = ((u64)ord_f32(s2.x) << 32) | ((u32)q0 << 8) | l0;
  const u64 f1 = ((u64)ord_f32(s2.y) << 32) | ((u32)(q0 + 1) << 8) | l1;
  const u64 b0 = __ballot(v0), b1 = __ballot(v1);
  if (lane == 0) {
    const u32 c = (u32)(__popcll(b0) + __popcll(b1));
    wval[wv] = c;
    winv[wv] = 128u - c;
  }
  __syncthreads();  // B0

  int nv = 0, voff = 0, ioff = 0;
  #pragma unroll
  for (int w = 0; w < 16; ++w) {
    const int c = (int)wval[w];
    nv += c;
    if (w < wv) { voff += c; ioff += (int)winv[w]; }
  }
  const int tinv = BQ - nv;
  const u64 below = (1ull << lane) - 1ull;
  const int vr0 = voff + (int)__popcll(b0 & below) + (int)__popcll(b1 & below);
  const int ir0 = ioff + (int)__popcll(~b0 & below) + (int)__popcll(~b1 & below);
  const int vr1 = vr0 + (v0 ? 1 : 0);
  const int ir1 = ir0 + (v0 ? 0 : 1);
  // valids -> compact key array; invalids -> FINAL outputs now (position
  // nv + (tinv-1-ir) = descending orig idx, exact reversed-stable; proven r3-r9)
  if (v0) cvk[vr0] = f0;
  else {
    const int ip = nv + (tinv - 1 - ir0);
    *reinterpret_cast<float4*>(boxes_g + (size_t)ip * 4) = bb0;
    scores_g[ip] = s2.x; labels_g[ip] = lf.x; keep_g[ip] = 0.0f;
  }
  if (v1) cvk[vr1] = f1;
  else {
    const int ip = nv + (tinv - 1 - ir1);
    *reinterpret_cast<float4*>(boxes_g + (size_t)ip * 4) = bb1;
    scores_g[ip] = s2.y; labels_g[ip] = lf.y; keep_g[ip] = 0.0f;
  }
  // zero-pad keys to the 64-boundary: key 0 < every valid key (ord(s>=0.05)
  // has the sign-flip bit set), so pads contribute 0 to every count.
  const int nvc = (nv + 63) >> 6;
  for (int pp = nv + tid; pp < (nvc << 6); pp += 1024) cvk[pp] = 0;
  __syncthreads();  // B1

  // ---- phase 2: register-blocked tiled rank pass ----
  // Item (sc_, jc): lane holds 4 slot-keys (sc_*256 + lane + {0,64,128,192});
  // j-chunk read as 32 x ds_read_b128 (2 keys each) -> 8 pairs/DS-instruction.
  {
    const int nvS = (nv + 255) >> 8;   // 256-slot super-chunks
    const int nitems = nvS * nvc;
    for (int it = wv; it < nitems; it += 16) {
      const int sc_ = it / nvc;
      const int jc = it - sc_ * nvc;
      const int sb = (sc_ << 8) + lane;
      const u64 ki0 = cvk[sb];          // junk beyond pad harmless (guarded below)
      const u64 ki1 = cvk[sb + 64];
      const u64 ki2 = cvk[sb + 128];
      const u64 ki3 = cvk[sb + 192];
      const ulonglong2* jp2 = reinterpret_cast<const ulonglong2*>(&cvk[jc << 6]);
      u32 c0 = 0, c1 = 0, c2 = 0, c3 = 0;
      #pragma unroll 4
      for (int l2 = 0; l2 < 32; ++l2) {
        const ulonglong2 kj = jp2[l2];
        c0 += ((kj.x > ki0) ? 1u : 0u) + ((kj.y > ki0) ? 1u : 0u);
        c1 += ((kj.x > ki1) ? 1u : 0u) + ((kj.y > ki1) ? 1u : 0u);
        c2 += ((kj.x > ki2) ? 1u : 0u) + ((kj.y > ki2) ? 1u : 0u);
        c3 += ((kj.x > ki3) ? 1u : 0u) + ((kj.y > ki3) ? 1u : 0u);
      }
      if (sb < nv && c0)       atomicAdd(&cgt_a[sb], c0);
      if (sb + 64 < nv && c1)  atomicAdd(&cgt_a[sb + 64], c1);
      if (sb + 128 < nv && c2) atomicAdd(&cgt_a[sb + 128], c2);
      if (sb + 192 < nv && c3) atomicAdd(&cgt_a[sb + 192], c3);
    }
  }
  __syncthreads();  // B2

  // ---- phase 3: sweep — place by rank; stage label/idx/score-bits/offset box ----
  for (int slot = tid; slot < nv; slot += 1024) {
    const u64 ki = cvk[slot];
    const u32 p = cgt_a[slot];           // sorted position (descending key)
    const u32 oi = (u32)(ki >> 8) & (BQ - 1);
    const u32 li = (u32)ki & 255u;
    sidx[p] = (u16)oi;
    lbp[p] = (u8)li;
    sco[p] = (u32)(ki >> 32) & 0x7FFFFFFFu;  // exact score bits (score > 0)
    const float lc = (float)li * 100000.0f;
    const float4 A = bx[oi];
    float4 Ao;
    Ao.x = A.x + lc; Ao.y = A.y + lc; Ao.z = A.z + lc; Ao.w = A.w + lc;
    bxo[p] = Ao;
  }
  for (int p = nv + tid; p < (nvc << 6); p += 1024) lbp[p] = 255;  // boundary pad
  __syncthreads();  // B3

  // ---- phase 4: ballot-match label ranks (gated per 64-chunk) + valid writeback ----
  int lA = 255, lB = 255; u32 rA = 0, rB = 0;
  {
    const int p = tid;
    if (p < (nvc << 6)) {
      lA = (int)lbp[p];
      u64 m = ~0ull;
      #pragma unroll
      for (int bt = 0; bt < 8; ++bt) {
        const u64 vb = __ballot(((lA >> bt) & 1));
        m &= ((lA >> bt) & 1) ? vb : ~vb;
      }
      rA = (u32)__popcll(m & below);
      if (lane == 63 - __builtin_clzll(m)) hist[(p >> 6) * 256 + lA] = (u16)__popcll(m);
    }
  }
  {
    const int p = tid + 1024;
    if (p < (nvc << 6)) {
      lB = (int)lbp[p];
      u64 m = ~0ull;
      #pragma unroll
      for (int bt = 0; bt < 8; ++bt) {
        const u64 vb = __ballot(((lB >> bt) & 1));
        m &= ((lB >> bt) & 1) ? vb : ~vb;
      }
      rB = (u32)__popcll(m & below);
      if (lane == 63 - __builtin_clzll(m)) hist[(p >> 6) * 256 + lB] = (u16)__popcll(m);
    }
  }
  // valid writeback (fire-and-forget; overlaps following phases' latency)
  for (int p = tid; p < nv; p += 1024) {
    const u32 oi = sidx[p];
    *reinterpret_cast<float4*>(boxes_g + (size_t)p * 4) = bx[oi];
    scores_g[p] = __uint_as_float(sco[p]);
    labels_g[p] = (float)lbp[p];
  }
  __syncthreads();  // B4

  // ---- phase 5: parallel per-label prefix over chunks (4 threads/label) ----
  {
    const int l = tid >> 2, t4 = tid & 3;
    u16 v0_[8]; u32 sum = 0;
    #pragma unroll
    for (int i = 0; i < 8; ++i) {
      v0_[i] = hist[(t4 * 8 + i) * 256 + l];
      sum += v0_[i];
    }
    u32 x = sum;
    u32 y = __shfl_up(x, 1, 64); if (t4 >= 1) x += y;
    y = __shfl_up(x, 2, 64);     if (t4 >= 2) x += y;
    u32 run = x - sum;  // exclusive prefix for this thread's chunk range
    #pragma unroll
    for (int i = 0; i < 8; ++i) {
      hist[(t4 * 8 + i) * 256 + l] = (u16)run;
      run += v0_[i];
    }
    if (t4 == 3) tot[l] = x;  // per-label total
  }
  __syncthreads();  // B5

  // ---- phase 6: inclusive label-offset scan by wave 0 ----
  if (tid < 64) {
    u32 carry = 0;
    for (int seg = 0; seg < 4; ++seg) {
      const int l = seg * 64 + tid;
      u32 x = tot[l];
      #pragma unroll
      for (int s = 1; s < 64; s <<= 1) {
        const u32 y = __shfl_up(x, s, 64);
        if (lane >= s) x += y;
      }
      scn[l] = x + carry;
      carry += __shfl(x, 63, 64);
    }
  }
  __syncthreads();  // B6

  // ---- phase 7: scatter group slots (ascending sorted position per label) ----
  u32 gA = ~0u, gB = ~0u;
  {
    const int p = tid;
    if (lA != 255) {
      const u32 st = (lA == 0) ? 0u : scn[lA - 1];
      gA = (u32)hist[(p >> 6) * 256 + lA] + rA;
      gpos[st + gA] = (u16)p;
    }
  }
  {
    const int p = tid + 1024;
    if (lB != 255) {
      const u32 st = (lB == 0) ? 0u : scn[lB - 1];
      gB = (u32)hist[(p >> 6) * 256 + lB] + rB;
      gpos[st + gB] = (u16)p;
    }
  }
  __syncthreads();  // B7

  // ---- phase 8: overlap bitmasks vs earlier same-label members ----
  // (cvk is dead as keys — reuse as the mask array)
  #pragma unroll
  for (int half = 0; half < 2; ++half) {
    const int p = tid + half * 1024;
    const int l = half ? lB : lA;
    const u32 g = half ? gB : gA;
    if (p < nv && g < 64) {
      const u32 st = (l == 0) ? 0u : scn[l - 1];
      const float4 Ao = bxo[p];
      const float areaA = fmaxf(Ao.z - Ao.x, 0.0f) * fmaxf(Ao.w - Ao.y, 0.0f);
      u64 m = 0;
      for (u32 r = 0; r < g; ++r) {
        const int p2 = gpos[st + r];
        const float4 Bo = bxo[p2];
        const float areaB = fmaxf(Bo.z - Bo.x, 0.0f) * fmaxf(Bo.w - Bo.y, 0.0f);
        const float ltx = fmaxf(Ao.x, Bo.x), lty = fmaxf(Ao.y, Bo.y);
        const float rbx = fminf(Ao.z, Bo.z), rby = fminf(Ao.w, Bo.w);
        const float iw = fmaxf(rbx - ltx, 0.0f), ih = fmaxf(rby - lty, 0.0f);
        const float inter = iw * ih;
        const float uni = (areaA + areaB) - inter;
        const float iou = inter / fmaxf(uni, 1e-6f);
        if (iou > 0.7f) m |= (1ull << r);
      }
      cvk[st + g] = m;
    }
  }
  __syncthreads();  // B8

  // ---- phase 9: per-label greedy resolution, writes keep_g directly ----
  if (tid < NL) {
    const int k = (int)tot[tid];
    if (k > 0) {
      const int st = (tid == 0) ? 0 : (int)scn[tid - 1];
      if (k <= 64) {
        u64 kept = 0;
        for (int r = 0; r < k; ++r) {
          const u64 m = cvk[st + r];
          const int keep = ((m & kept) == 0) ? 1 : 0;
          kept |= (u64)keep << r;
          keep_g[gpos[st + r]] = keep ? 1.0f : 0.0f;
        }
      } else {
        for (int a = 0; a < k; ++a) {
          const int p = gpos[st + a];
          const float4 Ao = bxo[p];
          const float areaA = fmaxf(Ao.z - Ao.x, 0.0f) * fmaxf(Ao.w - Ao.y, 0.0f);
          int keep = 1;
          for (int e = 0; e < a; ++e) {
            if (!grpk[st + e]) continue;
            const int p2 = gpos[st + e];
            const float4 Bo = bxo[p2];
            const float areaB = fmaxf(Bo.z - Bo.x, 0.0f) * fmaxf(Bo.w - Bo.y, 0.0f);
            const float ltx = fmaxf(Ao.x, Bo.x), lty = fmaxf(Ao.y, Bo.y);
            const float rbx = fminf(Ao.z, Bo.z), rby = fminf(Ao.w, Bo.w);
            const float iw = fmaxf(rbx - ltx, 0.0f), ih = fmaxf(rby - lty, 0.0f);
            const float inter = iw * ih;
            const float uni = (areaA + areaB) - inter;
            const float iou = inter / fmaxf(uni, 1e-6f);
            if (iou > 0.7f) { keep = 0; break; }
          }
          grpk[st + a] = (u8)keep;
          keep_g[p] = keep ? 1.0f : 0.0f;
        }
      }
    }
  }
}

extern "C" void kernel_launch(void* const* d_in, const int* in_sizes, int n_in,
                              void* d_out, int out_size, void* d_ws, size_t ws_size,
                              hipStream_t stream) {
  const float* logits = (const float*)d_in[0];
  const float* pboxes = (const float*)d_in[1];
  const int*   tsz    = (const int*)d_in[2];
  float* out = (float*)d_out;
  score_box_kernel<<<NB * BQ / 16, 256, 0, stream>>>(logits, pboxes, tsz, out);
  sort_nms_kernel<<<NB, 1024, 0, stream>>>(out);
}